// Round 12
// baseline (467.145 us; speedup 1.0000x reference)
//
#include <hip/hip_runtime.h>
#include <stdint.h>

#define BATCH 8
#define LSEQ 16384
#define HDIM 128
#define KSZ 65
#define PADW 32
#define LH (LSEQ*HDIM)
#define TL 256
#define NROWS (TL + 2*PADW)     // 320 staged Q rows
#define LBLKS (LSEQ/TL)         // 64
#define EXP_SHIFT 20.0f
#define SLOT 16384              // elems per full-tap W slot (32 KB)

#define WS_WBF_OFF 4096         // bf16 W-fragments start here; gsum f32[1024] at offset 0

typedef __attribute__((ext_vector_type(8))) short bf16x8;
typedef __attribute__((ext_vector_type(4))) short bf16x4;
typedef __attribute__((ext_vector_type(16))) float f32x16;

__device__ __forceinline__ unsigned short f2bf(float f) {
  unsigned int u = __float_as_uint(f);
  return (unsigned short)((u + 0x7FFFu + ((u >> 16) & 1u)) >> 16);  // RNE
}

// ---------------- K0: W [o][i][k] f32 -> per-tap fragment-ordered bf16 ----------------
// Wbf[k][kk][ob][hi2][l31][e] : tap k is one contiguous 32 KB slot, laid out exactly
// as the LDS slot, so global_load_lds stages it linearly. Frag: o=ob*32+l31, i=kk*16+hi2*8+e.
__global__ __launch_bounds__(256) void wcvt_kernel(const float* __restrict__ W,
                                                   unsigned short* __restrict__ Wbf) {
  __shared__ float lw[KSZ*HDIM];
  const int o = blockIdx.x;
  const float* src = W + (size_t)o * (HDIM*KSZ);
  for (int t = threadIdx.x; t < HDIM*KSZ; t += 256) lw[t] = src[t];
  __syncthreads();
  const int ob  = o >> 5;
  const int l31 = o & 31;
  for (int idx = threadIdx.x; idx < KSZ*HDIM; idx += 256) {
    const int k = idx >> 7;      // 0..64
    const int i = idx & 127;
    const int kk  = i >> 4;      // 0..7
    const int hi2 = (i >> 3) & 1;
    const int e   = i & 7;
    const size_t dst = (size_t)k*SLOT + kk*2048 + ob*512 + hi2*256 + l31*8 + e;
    Wbf[dst] = f2bf(lw[i*KSZ + k]);
  }
}

// stage one 32KB tap linearly into an LDS slot (4 waves x 8 x 1KB)
__device__ __forceinline__ void stage_tap(const unsigned short* __restrict__ gsrc,
                                          char* lbase, int w, int lane) {
  const char* gb = (const char*)gsrc;
#pragma unroll
  for (int r = 0; r < 8; ++r) {
    const int off = r*4096 + w*1024;   // 4 waves * 64 lanes * 16B = 4096B per round
    __builtin_amdgcn_global_load_lds(
        (const __attribute__((address_space(1))) unsigned int*)(gb + off + lane*16),
        (__attribute__((address_space(3))) unsigned int*)(lbase + off),
        16, 0, 0);
  }
}

// ---------------- K1: conv GEMM, 4 waves, 128x128xK64 wave tiles (zero read waste) ----------------
__global__ __launch_bounds__(256, 1) void conv_gate_kernel(
    const float* __restrict__ Qm, const float* __restrict__ Km,
    const unsigned short* __restrict__ Wfrag,
    float* __restrict__ Eout, float* __restrict__ gsum) {

  __shared__ __align__(16) char smem[147456];   // Qs 80K | Ws 2x32K ; reused as f32 red[]
  unsigned short* Qs = (unsigned short*)smem;
  char* WsBase = smem + 81920;

  const int tid  = threadIdx.x;
  const int lane = tid & 63;
  const int w    = tid >> 6;       // 0..3
  const int ks   = w & 1;          // K-half: input channels [ks*64, ks*64+64)
  const int wr   = w >> 1;         // 0..1 : 128-row band
  const int l31  = lane & 31;
  const int hi2  = lane >> 5;      // 0..1

  const int bx = blockIdx.x;
  const int b  = bx >> 6;
  const int l0 = (bx & 63) << 8;   // * TL

  // ---- stage Q rows [l0-32, l0+TL+32) as swizzled bf16 ----
  {
    const int r0 = tid >> 5;            // 0..7
    const int c4 = (tid & 31) << 2;     // 0..124 step 4
    const float* qbase = Qm + (size_t)b*LH + c4;
#pragma unroll
    for (int it = 0; it < NROWS/8; ++it) {
      const int r = it*8 + r0;
      const int grow = l0 - PADW + r;
      bf16x4 pk = {0, 0, 0, 0};
      if (grow >= 0 && grow < LSEQ) {
        const float4 qv = *(const float4*)(qbase + (size_t)grow*HDIM);
        pk[0] = (short)f2bf(qv.x); pk[1] = (short)f2bf(qv.y);
        pk[2] = (short)f2bf(qv.z); pk[3] = (short)f2bf(qv.w);
      }
      *(bf16x4*)(&Qs[r*HDIM + (c4 ^ ((r & 15) << 3))]) = pk;
    }
  }

  stage_tap(Wfrag, WsBase, w, lane);   // tap 0 -> slot 0

  f32x16 acc[4][4] = {};

  __syncthreads();   // Q staged + tap0 landed (full drain once)

  const int arow0 = wr*128 + l31;
  const int bB = hi2*256 + l31*8;      // + (ks*4+c)*2048 + nf*512

  for (int k = 0; k < KSZ; ++k) {
    const unsigned short* slot = (const unsigned short*)(WsBase + (k & 1)*32768);
    if (k < KSZ-1)
      stage_tap(Wfrag + (size_t)(k+1)*SLOT, WsBase + ((k+1) & 1)*32768, w, lane);

    const int rb = k + arow0;          // sliding window: tap k shifts A rows by one
    const int xa = (rb & 15) << 3;     // rows rb,+32,+64,+96 share (r&15)

#pragma unroll
    for (int c = 0; c < 4; ++c) {
      const int i0 = (ks*64 + c*16 + hi2*8) ^ xa;
      bf16x8 A0 = *(const bf16x8*)(&Qs[(rb     )*HDIM + i0]);
      bf16x8 A1 = *(const bf16x8*)(&Qs[(rb + 32)*HDIM + i0]);
      bf16x8 A2 = *(const bf16x8*)(&Qs[(rb + 64)*HDIM + i0]);
      bf16x8 A3 = *(const bf16x8*)(&Qs[(rb + 96)*HDIM + i0]);
      const unsigned short* bp = slot + (ks*4 + c)*2048 + bB;
      bf16x8 B0 = *(const bf16x8*)(bp       );
      bf16x8 B1 = *(const bf16x8*)(bp +  512);
      bf16x8 B2 = *(const bf16x8*)(bp + 1024);
      bf16x8 B3 = *(const bf16x8*)(bp + 1536);
      acc[0][0] = __builtin_amdgcn_mfma_f32_32x32x16_bf16(A0, B0, acc[0][0], 0, 0, 0);
      acc[0][1] = __builtin_amdgcn_mfma_f32_32x32x16_bf16(A0, B1, acc[0][1], 0, 0, 0);
      acc[0][2] = __builtin_amdgcn_mfma_f32_32x32x16_bf16(A0, B2, acc[0][2], 0, 0, 0);
      acc[0][3] = __builtin_amdgcn_mfma_f32_32x32x16_bf16(A0, B3, acc[0][3], 0, 0, 0);
      acc[1][0] = __builtin_amdgcn_mfma_f32_32x32x16_bf16(A1, B0, acc[1][0], 0, 0, 0);
      acc[1][1] = __builtin_amdgcn_mfma_f32_32x32x16_bf16(A1, B1, acc[1][1], 0, 0, 0);
      acc[1][2] = __builtin_amdgcn_mfma_f32_32x32x16_bf16(A1, B2, acc[1][2], 0, 0, 0);
      acc[1][3] = __builtin_amdgcn_mfma_f32_32x32x16_bf16(A1, B3, acc[1][3], 0, 0, 0);
      acc[2][0] = __builtin_amdgcn_mfma_f32_32x32x16_bf16(A2, B0, acc[2][0], 0, 0, 0);
      acc[2][1] = __builtin_amdgcn_mfma_f32_32x32x16_bf16(A2, B1, acc[2][1], 0, 0, 0);
      acc[2][2] = __builtin_amdgcn_mfma_f32_32x32x16_bf16(A2, B2, acc[2][2], 0, 0, 0);
      acc[2][3] = __builtin_amdgcn_mfma_f32_32x32x16_bf16(A2, B3, acc[2][3], 0, 0, 0);
      acc[3][0] = __builtin_amdgcn_mfma_f32_32x32x16_bf16(A3, B0, acc[3][0], 0, 0, 0);
      acc[3][1] = __builtin_amdgcn_mfma_f32_32x32x16_bf16(A3, B1, acc[3][1], 0, 0, 0);
      acc[3][2] = __builtin_amdgcn_mfma_f32_32x32x16_bf16(A3, B2, acc[3][2], 0, 0, 0);
      acc[3][3] = __builtin_amdgcn_mfma_f32_32x32x16_bf16(A3, B3, acc[3][3], 0, 0, 0);
    }
    asm volatile("s_waitcnt vmcnt(0)" ::: "memory");  // own stage loads landed (L2-fast)
    __builtin_amdgcn_s_barrier();                     // publish: slot k+1 ready for ALL waves
  }

  // ---- K-split reduction: ks=1 partial -> LDS -> ks=0 adds ----
  __syncthreads();                            // all LDS reads of Qs/Ws complete
  float* red = (float*)smem;                  // 2 regions x 64 KB (reuse Qs+Ws)
  float* reg = red + wr*16384 + lane*4;
  if (ks == 1) {
#pragma unroll
    for (int q = 0; q < 64; ++q) {
      const int mf = q >> 4, nf = (q >> 2) & 3, r4 = (q & 3) << 2;
      float4 v;
      v.x = acc[mf][nf][r4];   v.y = acc[mf][nf][r4+1];
      v.z = acc[mf][nf][r4+2]; v.w = acc[mf][nf][r4+3];
      *(float4*)(reg + q*256) = v;
    }
  }
  __syncthreads();

  if (ks == 0) {
#pragma unroll
    for (int q = 0; q < 64; ++q) {
      const int mf = q >> 4, nf = (q >> 2) & 3, r4 = (q & 3) << 2;
      const float4 v = *(const float4*)(reg + q*256);
      acc[mf][nf][r4]   += v.x; acc[mf][nf][r4+1] += v.y;
      acc[mf][nf][r4+2] += v.z; acc[mf][nf][r4+3] += v.w;
    }
    // ---- epilogue: gate by K, exp-shift, store E, per-column partial sums ----
    float psum[4] = {0.f, 0.f, 0.f, 0.f};
#pragma unroll
    for (int mf = 0; mf < 4; ++mf) {
#pragma unroll
      for (int r = 0; r < 16; ++r) {
        const int row = wr*128 + mf*32 + (r & 3) + 8*(r >> 2) + 4*hi2;  // C/D (m74/m101)
        const size_t gb = (size_t)b*LH + (size_t)(l0 + row)*HDIM + l31;
#pragma unroll
        for (int nf = 0; nf < 4; ++nf) {                                // col = lane&31
          const float s = acc[mf][nf][r] * Km[gb + nf*32];
          const float e = __expf(s - EXP_SHIFT);
          Eout[gb + nf*32] = e;
          psum[nf] += e;
        }
      }
    }
#pragma unroll
    for (int nf = 0; nf < 4; ++nf)
      psum[nf] += __shfl_xor(psum[nf], 32);   // fold hi2 halves (same column)
    if (hi2 == 0) {
#pragma unroll
      for (int nf = 0; nf < 4; ++nf)
        atomicAdd(&gsum[b*HDIM + nf*32 + l31], psum[nf]);
    }
  }
}

// ---------------- K2: Z = E * V / gsum (in place on d_out) ----------------
__global__ __launch_bounds__(256) void finalize_kernel(float* __restrict__ out,
                                                       const float* __restrict__ V,
                                                       const float* __restrict__ gsum) {
  const int total4 = (BATCH*LH) >> 2;
  const int stride = gridDim.x * blockDim.x;
  for (int f = blockIdx.x*blockDim.x + threadIdx.x; f < total4; f += stride) {
    const float4 e = ((const float4*)out)[f];
    const float4 v = ((const float4*)V)[f];
    const int e0 = f << 2;
    const float* gs = gsum + ((e0 >> 21) << 7) + (e0 & 127);   // b*128 + h0
    float4 z;
    z.x = e.x * v.x / gs[0];
    z.y = e.y * v.y / gs[1];
    z.z = e.z * v.z / gs[2];
    z.w = e.w * v.w / gs[3];
    ((float4*)out)[f] = z;
  }
}

extern "C" void kernel_launch(void* const* d_in, const int* in_sizes, int n_in,
                              void* d_out, int out_size, void* d_ws, size_t ws_size,
                              hipStream_t stream) {
  (void)in_sizes; (void)n_in; (void)out_size; (void)ws_size;
  const float* Q = (const float*)d_in[0];
  const float* K = (const float*)d_in[1];
  const float* V = (const float*)d_in[2];
  const float* W = (const float*)d_in[3];
  float* out  = (float*)d_out;
  float* gsum = (float*)d_ws;
  unsigned short* Wbf = (unsigned short*)((char*)d_ws + WS_WBF_OFF);

  hipMemsetAsync(d_ws, 0, BATCH*HDIM*sizeof(float), stream);          // gsum = 0
  wcvt_kernel<<<HDIM, 256, 0, stream>>>(W, Wbf);                      // W -> per-tap frag order
  conv_gate_kernel<<<BATCH*LBLKS, 256, 0, stream>>>(Q, K, Wbf, out, gsum);
  finalize_kernel<<<2048, 256, 0, stream>>>(out, V, gsum);
}

// Round 13
// 278.759 us; speedup vs baseline: 1.6758x; 1.6758x over previous
//
#include <hip/hip_runtime.h>
#include <stdint.h>

#define BATCH 8
#define LSEQ 16384
#define HDIM 128
#define KSZ 65
#define PADW 32
#define LH (LSEQ*HDIM)
#define TL 256
#define NROWS (TL + 2*PADW)     // 320 staged Q rows
#define LBLKS (LSEQ/TL)         // 64
#define EXP_SHIFT 20.0f
#define SLOT 16384              // elems per full-tap W slot (32 KB)

#define WS_WBF_OFF 4096         // bf16 W-fragments start here; gsum f32[1024] at offset 0

typedef __attribute__((ext_vector_type(8))) short bf16x8;
typedef __attribute__((ext_vector_type(4))) short bf16x4;
typedef __attribute__((ext_vector_type(16))) float f32x16;

__device__ __forceinline__ unsigned short f2bf(float f) {
  unsigned int u = __float_as_uint(f);
  return (unsigned short)((u + 0x7FFFu + ((u >> 16) & 1u)) >> 16);  // RNE
}

// ---------------- K0: W [o][i][k] f32 -> per-tap fragment-ordered bf16 ----------------
// Wbf[k][kk][ob][hi2][l31][e] : tap k is one contiguous 32 KB slot, laid out exactly
// as the LDS slot, so global_load_lds stages it linearly. Frag: o=ob*32+l31, i=kk*16+hi2*8+e.
__global__ __launch_bounds__(256) void wcvt_kernel(const float* __restrict__ W,
                                                   unsigned short* __restrict__ Wbf) {
  __shared__ float lw[KSZ*HDIM];
  const int o = blockIdx.x;
  const float* src = W + (size_t)o * (HDIM*KSZ);
  for (int t = threadIdx.x; t < HDIM*KSZ; t += 256) lw[t] = src[t];
  __syncthreads();
  const int ob  = o >> 5;
  const int l31 = o & 31;
  for (int idx = threadIdx.x; idx < KSZ*HDIM; idx += 256) {
    const int k = idx >> 7;      // 0..64
    const int i = idx & 127;
    const int kk  = i >> 4;      // 0..7
    const int hi2 = (i >> 3) & 1;
    const int e   = i & 7;
    const size_t dst = (size_t)k*SLOT + kk*2048 + ob*512 + hi2*256 + l31*8 + e;
    Wbf[dst] = f2bf(lw[i*KSZ + k]);
  }
}

// stage one 32KB tap linearly into an LDS slot (8 waves x 4 x 1KB)
__device__ __forceinline__ void stage_tap(const unsigned short* __restrict__ gsrc,
                                          char* lbase, int w, int lane) {
  const char* gb = (const char*)gsrc;
#pragma unroll
  for (int r = 0; r < 4; ++r) {
    const int off = r*8192 + w*1024;   // 8 waves * 64 lanes * 16B = 8192B per round
    __builtin_amdgcn_global_load_lds(
        (const __attribute__((address_space(1))) unsigned int*)(gb + off + lane*16),
        (__attribute__((address_space(3))) unsigned int*)(lbase + off),
        16, 0, 0);
  }
}

// ---------------- K1: conv GEMM, r8 geometry + cross-tap A-register prefetch ----------------
__global__ __launch_bounds__(512, 2) void conv_gate_kernel(
    const float* __restrict__ Qm, const float* __restrict__ Km,
    const unsigned short* __restrict__ Wfrag,
    float* __restrict__ Eout, float* __restrict__ gsum) {

  __shared__ __align__(16) char smem[147456];           // Qs 80K | Ws 2x32K ; reused as f32 red[]
  unsigned short* Qs = (unsigned short*)smem;
  char* WsBase = smem + 81920;

  const int tid  = threadIdx.x;
  const int lane = tid & 63;
  const int w    = tid >> 6;       // 0..7
  const int ks   = w & 1;          // K-half: input channels [ks*64, ks*64+64)
  const int wc   = (w >> 1) & 1;   // 0..1 : 64-col band
  const int wr   = w >> 2;         // 0..1 : 128-row band
  const int l31  = lane & 31;
  const int hi2  = lane >> 5;      // 0..1

  const int bx = blockIdx.x;
  const int b  = bx >> 6;
  const int l0 = (bx & 63) << 8;   // * TL

  // ---- stage Q rows [l0-32, l0+TL+32) as swizzled bf16 ----
  {
    const int r0 = tid >> 5;            // 0..15
    const int c4 = (tid & 31) << 2;     // 0..124 step 4
    const float* qbase = Qm + (size_t)b*LH + c4;
#pragma unroll
    for (int it = 0; it < NROWS/16; ++it) {
      const int r = it*16 + r0;
      const int grow = l0 - PADW + r;
      bf16x4 pk = {0, 0, 0, 0};
      if (grow >= 0 && grow < LSEQ) {
        const float4 qv = *(const float4*)(qbase + (size_t)grow*HDIM);
        pk[0] = (short)f2bf(qv.x); pk[1] = (short)f2bf(qv.y);
        pk[2] = (short)f2bf(qv.z); pk[3] = (short)f2bf(qv.w);
      }
      *(bf16x4*)(&Qs[r*HDIM + (c4 ^ ((r & 15) << 3))]) = pk;
    }
  }

  stage_tap(Wfrag, WsBase, w, lane);   // tap 0 -> slot 0

  f32x16 acc[4][2] = {};

  __syncthreads();   // Q staged + tap0 landed (full drain once)

  const int arow0 = wr*128 + l31;
  const int bbase = wc*1024 + lane*8;       // + nf*512 + (ks*4+c)*2048

  // A-frag loads for tap KK, chunk c -> 4 named frags (reads ONLY immutable Qs,
  // so they may be issued before the slot-publish barrier = cross-tap overlap)
#define LOADA(D, KK, c) { \
    const int rb_ = (KK) + arow0; \
    const int xa_ = (rb_ & 15) << 3; \
    const int i0_ = (ks*64 + (c)*16 + hi2*8) ^ xa_; \
    D[0] = *(const bf16x8*)(&Qs[(rb_     )*HDIM + i0_]); \
    D[1] = *(const bf16x8*)(&Qs[(rb_ + 32)*HDIM + i0_]); \
    D[2] = *(const bf16x8*)(&Qs[(rb_ + 64)*HDIM + i0_]); \
    D[3] = *(const bf16x8*)(&Qs[(rb_ + 96)*HDIM + i0_]); \
  }
#define LOADB(B, c) { \
    const unsigned short* bp_ = slot + (ks*4 + (c))*2048 + bbase; \
    B[0] = *(const bf16x8*)(bp_); \
    B[1] = *(const bf16x8*)(bp_ + 512); \
  }
#define MM(A, B) \
    acc[0][0] = __builtin_amdgcn_mfma_f32_32x32x16_bf16(A[0], B[0], acc[0][0], 0, 0, 0); \
    acc[0][1] = __builtin_amdgcn_mfma_f32_32x32x16_bf16(A[0], B[1], acc[0][1], 0, 0, 0); \
    acc[1][0] = __builtin_amdgcn_mfma_f32_32x32x16_bf16(A[1], B[0], acc[1][0], 0, 0, 0); \
    acc[1][1] = __builtin_amdgcn_mfma_f32_32x32x16_bf16(A[1], B[1], acc[1][1], 0, 0, 0); \
    acc[2][0] = __builtin_amdgcn_mfma_f32_32x32x16_bf16(A[2], B[0], acc[2][0], 0, 0, 0); \
    acc[2][1] = __builtin_amdgcn_mfma_f32_32x32x16_bf16(A[2], B[1], acc[2][1], 0, 0, 0); \
    acc[3][0] = __builtin_amdgcn_mfma_f32_32x32x16_bf16(A[3], B[0], acc[3][0], 0, 0, 0); \
    acc[3][1] = __builtin_amdgcn_mfma_f32_32x32x16_bf16(A[3], B[1], acc[3][1], 0, 0, 0);

  // One tap: consume CUR (loaded last tap), refill NXT with tap k+1's A-frags.
  // B per-chunk just-in-time (live B <= 2 pairs). vmcnt(0)+barrier publishes slot k+1.
#define TAPBODY(C0, C1, C2, C3, N0, N1, N2, N3, K) { \
    const unsigned short* slot = (const unsigned short*)(WsBase + ((K) & 1)*32768); \
    if ((K) < KSZ-1) \
      stage_tap(Wfrag + (size_t)((K)+1)*SLOT, WsBase + (((K)+1) & 1)*32768, w, lane); \
    const int kn = ((K)+1 < KSZ) ? (K)+1 : (K); \
    bf16x8 B0[2], B1[2], B2[2], B3[2]; \
    LOADB(B0, 0) \
    LOADB(B1, 1) \
    MM(C0, B0)  LOADA(N0, kn, 0) \
    LOADB(B2, 2) \
    MM(C1, B1)  LOADA(N1, kn, 1) \
    LOADB(B3, 3) \
    MM(C2, B2)  LOADA(N2, kn, 2) \
    MM(C3, B3)  LOADA(N3, kn, 3) \
    asm volatile("s_waitcnt vmcnt(0)" ::: "memory"); \
    __builtin_amdgcn_s_barrier(); \
  }

  bf16x8 AX0[4], AX1[4], AX2[4], AX3[4];
  bf16x8 AY0[4], AY1[4], AY2[4], AY3[4];

  LOADA(AX0, 0, 0) LOADA(AX1, 0, 1) LOADA(AX2, 0, 2) LOADA(AX3, 0, 3)   // prologue: tap 0 A

  for (int k = 0; k < KSZ-1; k += 2) {    // taps 0..63 in even/odd pairs
    TAPBODY(AX0, AX1, AX2, AX3, AY0, AY1, AY2, AY3, k)
    TAPBODY(AY0, AY1, AY2, AY3, AX0, AX1, AX2, AX3, k+1)
  }
  TAPBODY(AX0, AX1, AX2, AX3, AY0, AY1, AY2, AY3, KSZ-1)   // tap 64 (clamped refill)
#undef TAPBODY
#undef LOADA
#undef LOADB
#undef MM

  // ---- K-split reduction: ks=1 partial -> LDS -> ks=0 adds ----
  float* red = (float*)smem;                 // 4 regions x 32 KB, reuse Qs+Ws
  const int widx = wr*2 + wc;
  float* reg = red + widx*8192 + lane*4;
  if (ks == 1) {
#pragma unroll
    for (int e4 = 0; e4 < 32; ++e4) {
      const int mfr = e4 >> 3, nf = (e4 >> 2) & 1, r4 = (e4 & 3) << 2;
      float4 v;
      v.x = acc[mfr][nf][r4];   v.y = acc[mfr][nf][r4+1];
      v.z = acc[mfr][nf][r4+2]; v.w = acc[mfr][nf][r4+3];
      *(float4*)(reg + e4*256) = v;
    }
  }
  __syncthreads();

  if (ks == 0) {
#pragma unroll
    for (int e4 = 0; e4 < 32; ++e4) {
      const int mfr = e4 >> 3, nf = (e4 >> 2) & 1, r4 = (e4 & 3) << 2;
      const float4 v = *(const float4*)(reg + e4*256);
      acc[mfr][nf][r4]   += v.x; acc[mfr][nf][r4+1] += v.y;
      acc[mfr][nf][r4+2] += v.z; acc[mfr][nf][r4+3] += v.w;
    }
    // ---- epilogue: gate by K, exp-shift, store E, per-column partial sums ----
    float psum[2] = {0.f, 0.f};
#pragma unroll
    for (int mfr = 0; mfr < 4; ++mfr) {
#pragma unroll
      for (int r = 0; r < 16; ++r) {
        const int row = wr*128 + mfr*32 + (r & 3) + 8*(r >> 2) + 4*hi2;  // C/D (m74/m101)
        const size_t gb = (size_t)b*LH + (size_t)(l0 + row)*HDIM + wc*64 + l31;
#pragma unroll
        for (int nf = 0; nf < 2; ++nf) {                                 // col = lane&31
          const float s = acc[mfr][nf][r] * Km[gb + nf*32];
          const float e = __expf(s - EXP_SHIFT);
          Eout[gb + nf*32] = e;
          psum[nf] += e;
        }
      }
    }
    psum[0] += __shfl_xor(psum[0], 32);   // fold hi2 halves (same column)
    psum[1] += __shfl_xor(psum[1], 32);
    if (hi2 == 0) {
      atomicAdd(&gsum[b*HDIM + wc*64 + l31],      psum[0]);
      atomicAdd(&gsum[b*HDIM + wc*64 + 32 + l31], psum[1]);
    }
  }
}

// ---------------- K2: Z = E * V / gsum (in place on d_out) ----------------
__global__ __launch_bounds__(256) void finalize_kernel(float* __restrict__ out,
                                                       const float* __restrict__ V,
                                                       const float* __restrict__ gsum) {
  const int total4 = (BATCH*LH) >> 2;
  const int stride = gridDim.x * blockDim.x;
  for (int f = blockIdx.x*blockDim.x + threadIdx.x; f < total4; f += stride) {
    const float4 e = ((const float4*)out)[f];
    const float4 v = ((const float4*)V)[f];
    const int e0 = f << 2;
    const float* gs = gsum + ((e0 >> 21) << 7) + (e0 & 127);   // b*128 + h0
    float4 z;
    z.x = e.x * v.x / gs[0];
    z.y = e.y * v.y / gs[1];
    z.z = e.z * v.z / gs[2];
    z.w = e.w * v.w / gs[3];
    ((float4*)out)[f] = z;
  }
}

extern "C" void kernel_launch(void* const* d_in, const int* in_sizes, int n_in,
                              void* d_out, int out_size, void* d_ws, size_t ws_size,
                              hipStream_t stream) {
  (void)in_sizes; (void)n_in; (void)out_size; (void)ws_size;
  const float* Q = (const float*)d_in[0];
  const float* K = (const float*)d_in[1];
  const float* V = (const float*)d_in[2];
  const float* W = (const float*)d_in[3];
  float* out  = (float*)d_out;
  float* gsum = (float*)d_ws;
  unsigned short* Wbf = (unsigned short*)((char*)d_ws + WS_WBF_OFF);

  hipMemsetAsync(d_ws, 0, BATCH*HDIM*sizeof(float), stream);          // gsum = 0
  wcvt_kernel<<<HDIM, 256, 0, stream>>>(W, Wbf);                      // W -> per-tap frag order
  conv_gate_kernel<<<BATCH*LBLKS, 512, 0, stream>>>(Q, K, Wbf, out, gsum);
  finalize_kernel<<<2048, 256, 0, stream>>>(out, V, gsum);
}

// Round 14
// 277.779 us; speedup vs baseline: 1.6817x; 1.0035x over previous
//
#include <hip/hip_runtime.h>
#include <stdint.h>

#define BATCH 8
#define LSEQ 16384
#define HDIM 128
#define KSZ 65
#define PADW 32
#define LH (LSEQ*HDIM)
#define TL 256
#define NROWS (TL + 2*PADW)     // 320 staged Q rows
#define LBLKS (LSEQ/TL)         // 64
#define EXP_SHIFT 20.0f
#define SLOT 16384              // elems per full-tap W slot (32 KB)

#define WS_WBF_OFF 4096         // bf16 W-fragments start here; gsum f32[1024] at offset 0

typedef __attribute__((ext_vector_type(8))) short bf16x8;
typedef __attribute__((ext_vector_type(4))) short bf16x4;
typedef __attribute__((ext_vector_type(16))) float f32x16;

__device__ __forceinline__ unsigned short f2bf(float f) {
  unsigned int u = __float_as_uint(f);
  return (unsigned short)((u + 0x7FFFu + ((u >> 16) & 1u)) >> 16);  // RNE
}

// ---------------- K0: W [o][i][k] f32 -> per-tap fragment-ordered bf16 ----------------
// Wbf[k][kk][ob][hi2][l31][e] : tap k is one contiguous 32 KB slot, laid out exactly
// as the LDS slot, so global_load_lds stages it linearly. Frag: o=ob*32+l31, i=kk*16+hi2*8+e.
__global__ __launch_bounds__(256) void wcvt_kernel(const float* __restrict__ W,
                                                   unsigned short* __restrict__ Wbf) {
  __shared__ float lw[KSZ*HDIM];
  const int o = blockIdx.x;
  const float* src = W + (size_t)o * (HDIM*KSZ);
  for (int t = threadIdx.x; t < HDIM*KSZ; t += 256) lw[t] = src[t];
  __syncthreads();
  const int ob  = o >> 5;
  const int l31 = o & 31;
  for (int idx = threadIdx.x; idx < KSZ*HDIM; idx += 256) {
    const int k = idx >> 7;      // 0..64
    const int i = idx & 127;
    const int kk  = i >> 4;      // 0..7
    const int hi2 = (i >> 3) & 1;
    const int e   = i & 7;
    const size_t dst = (size_t)k*SLOT + kk*2048 + ob*512 + hi2*256 + l31*8 + e;
    Wbf[dst] = f2bf(lw[i*KSZ + k]);
  }
}

// stage one 32KB tap linearly into an LDS slot (8 waves x 4 x 1KB)
__device__ __forceinline__ void stage_tap(const unsigned short* __restrict__ gsrc,
                                          char* lbase, int w, int lane) {
  const char* gb = (const char*)gsrc;
#pragma unroll
  for (int r = 0; r < 4; ++r) {
    const int off = r*8192 + w*1024;   // 8 waves * 64 lanes * 16B = 8192B per round
    __builtin_amdgcn_global_load_lds(
        (const __attribute__((address_space(1))) unsigned int*)(gb + off + lane*16),
        (__attribute__((address_space(3))) unsigned int*)(lbase + off),
        16, 0, 0);
  }
}

// ---------------- K1: conv GEMM, r8 geometry + wave anti-phased chunk order ----------------
__global__ __launch_bounds__(512, 2) void conv_gate_kernel(
    const float* __restrict__ Qm, const float* __restrict__ Km,
    const unsigned short* __restrict__ Wfrag,
    float* __restrict__ Eout, float* __restrict__ gsum) {

  __shared__ __align__(16) char smem[147456];           // Qs 80K | Ws 2x32K ; reused as f32 red[]
  unsigned short* Qs = (unsigned short*)smem;
  char* WsBase = smem + 81920;

  const int tid  = threadIdx.x;
  const int lane = tid & 63;
  const int w    = tid >> 6;       // 0..7
  const int ks   = w & 1;          // K-half: input channels [ks*64, ks*64+64)
  const int wc   = (w >> 1) & 1;   // 0..1 : 64-col band
  const int wr   = w >> 2;         // 0..1 : 128-row band
  const int l31  = lane & 31;
  const int hi2  = lane >> 5;      // 0..1

  // anti-phase: waves 0-3 process chunks 0,1,2,3; waves 4-7 process 2,3,0,1.
  // (waves w and w+4 share a SIMD under the standard w%4 round-robin, so each
  // SIMD pairs a read-phase wave with an MFMA-phase wave -> pipes overlap)
  const int po = ((w >> 2) & 1) << 1;

  const int bx = blockIdx.x;
  const int b  = bx >> 6;
  const int l0 = (bx & 63) << 8;   // * TL

  // ---- stage Q rows [l0-32, l0+TL+32) as swizzled bf16 ----
  {
    const int r0 = tid >> 5;            // 0..15
    const int c4 = (tid & 31) << 2;     // 0..124 step 4
    const float* qbase = Qm + (size_t)b*LH + c4;
#pragma unroll
    for (int it = 0; it < NROWS/16; ++it) {
      const int r = it*16 + r0;
      const int grow = l0 - PADW + r;
      bf16x4 pk = {0, 0, 0, 0};
      if (grow >= 0 && grow < LSEQ) {
        const float4 qv = *(const float4*)(qbase + (size_t)grow*HDIM);
        pk[0] = (short)f2bf(qv.x); pk[1] = (short)f2bf(qv.y);
        pk[2] = (short)f2bf(qv.z); pk[3] = (short)f2bf(qv.w);
      }
      *(bf16x4*)(&Qs[r*HDIM + (c4 ^ ((r & 15) << 3))]) = pk;
    }
  }

  stage_tap(Wfrag, WsBase, w, lane);   // tap 0 -> slot 0

  f32x16 acc[4][2] = {};

  __syncthreads();   // Q staged + tap0 landed (full drain here, once)

  const int arow0 = wr*128 + l31;
  const int bbase = wc*1024 + lane*8;    // + nf*512 + (ks*4+cc)*2048

  // cs = sequence position (compile-time, names registers); cc = actual chunk (runtime addr)
#define LOADC(cs, A0,A1,A2,A3,B0,B1) { \
    const int cc = ((cs) + po) & 3; \
    const int i0 = (ks*64 + cc*16 + hi2*8) ^ xa; \
    A0 = *(const bf16x8*)(&Qs[(rb     )*HDIM + i0]); \
    A1 = *(const bf16x8*)(&Qs[(rb + 32)*HDIM + i0]); \
    A2 = *(const bf16x8*)(&Qs[(rb + 64)*HDIM + i0]); \
    A3 = *(const bf16x8*)(&Qs[(rb + 96)*HDIM + i0]); \
    B0 = *(const bf16x8*)(&slot[(ks*4 + cc)*2048 + bbase]); \
    B1 = *(const bf16x8*)(&slot[(ks*4 + cc)*2048 + bbase + 512]); \
  }
#define MM(A0,A1,A2,A3,B0,B1) \
    acc[0][0] = __builtin_amdgcn_mfma_f32_32x32x16_bf16(A0, B0, acc[0][0], 0, 0, 0); \
    acc[0][1] = __builtin_amdgcn_mfma_f32_32x32x16_bf16(A0, B1, acc[0][1], 0, 0, 0); \
    acc[1][0] = __builtin_amdgcn_mfma_f32_32x32x16_bf16(A1, B0, acc[1][0], 0, 0, 0); \
    acc[1][1] = __builtin_amdgcn_mfma_f32_32x32x16_bf16(A1, B1, acc[1][1], 0, 0, 0); \
    acc[2][0] = __builtin_amdgcn_mfma_f32_32x32x16_bf16(A2, B0, acc[2][0], 0, 0, 0); \
    acc[2][1] = __builtin_amdgcn_mfma_f32_32x32x16_bf16(A2, B1, acc[2][1], 0, 0, 0); \
    acc[3][0] = __builtin_amdgcn_mfma_f32_32x32x16_bf16(A3, B0, acc[3][0], 0, 0, 0); \
    acc[3][1] = __builtin_amdgcn_mfma_f32_32x32x16_bf16(A3, B1, acc[3][1], 0, 0, 0);

  for (int k = 0; k < KSZ; ++k) {
    const unsigned short* slot = (const unsigned short*)(WsBase + (k & 1)*32768);
    if (k < KSZ-1)
      stage_tap(Wfrag + (size_t)(k+1)*SLOT, WsBase + ((k+1) & 1)*32768, w, lane);

    const int rb = k + arow0;               // sliding window: tap k shifts A rows by one
    const int xa = (rb & 15) << 3;          // rows rb,+32,+64,+96 share (r&15)

    bf16x8 a0,a1,a2,a3,b0,b1, c0,c1,c2,c3,d0,d1;
    LOADC(0, a0,a1,a2,a3,b0,b1)
    LOADC(1, c0,c1,c2,c3,d0,d1)
    MM(a0,a1,a2,a3,b0,b1)                   // seq 0 MFMAs overlap seq 2 loads
    LOADC(2, a0,a1,a2,a3,b0,b1)
    MM(c0,c1,c2,c3,d0,d1)                   // seq 1
    LOADC(3, c0,c1,c2,c3,d0,d1)
    MM(a0,a1,a2,a3,b0,b1)                   // seq 2
    MM(c0,c1,c2,c3,d0,d1)                   // seq 3

    asm volatile("s_waitcnt vmcnt(0)" ::: "memory");  // own stage loads landed (L2-fast)
    __builtin_amdgcn_s_barrier();                     // publish: slot k+1 ready for ALL waves
  }
#undef LOADC
#undef MM

  // ---- K-split reduction: ks=1 partial -> LDS -> ks=0 adds ----
  float* red = (float*)smem;                 // 4 regions x 32 KB, reuse Qs+Ws
  const int widx = wr*2 + wc;
  float* reg = red + widx*8192 + lane*4;
  if (ks == 1) {
#pragma unroll
    for (int e4 = 0; e4 < 32; ++e4) {
      const int mfr = e4 >> 3, nf = (e4 >> 2) & 1, r4 = (e4 & 3) << 2;
      float4 v;
      v.x = acc[mfr][nf][r4];   v.y = acc[mfr][nf][r4+1];
      v.z = acc[mfr][nf][r4+2]; v.w = acc[mfr][nf][r4+3];
      *(float4*)(reg + e4*256) = v;
    }
  }
  __syncthreads();

  if (ks == 0) {
#pragma unroll
    for (int e4 = 0; e4 < 32; ++e4) {
      const int mfr = e4 >> 3, nf = (e4 >> 2) & 1, r4 = (e4 & 3) << 2;
      const float4 v = *(const float4*)(reg + e4*256);
      acc[mfr][nf][r4]   += v.x; acc[mfr][nf][r4+1] += v.y;
      acc[mfr][nf][r4+2] += v.z; acc[mfr][nf][r4+3] += v.w;
    }
    // ---- epilogue: gate by K, exp-shift, store E, per-column partial sums ----
    float psum[2] = {0.f, 0.f};
#pragma unroll
    for (int mfr = 0; mfr < 4; ++mfr) {
#pragma unroll
      for (int r = 0; r < 16; ++r) {
        const int row = wr*128 + mfr*32 + (r & 3) + 8*(r >> 2) + 4*hi2;  // C/D (m74/m101)
        const size_t gb = (size_t)b*LH + (size_t)(l0 + row)*HDIM + wc*64 + l31;
#pragma unroll
        for (int nf = 0; nf < 2; ++nf) {                                 // col = lane&31
          const float s = acc[mfr][nf][r] * Km[gb + nf*32];
          const float e = __expf(s - EXP_SHIFT);
          Eout[gb + nf*32] = e;
          psum[nf] += e;
        }
      }
    }
    psum[0] += __shfl_xor(psum[0], 32);   // fold hi2 halves (same column)
    psum[1] += __shfl_xor(psum[1], 32);
    if (hi2 == 0) {
      atomicAdd(&gsum[b*HDIM + wc*64 + l31],      psum[0]);
      atomicAdd(&gsum[b*HDIM + wc*64 + 32 + l31], psum[1]);
    }
  }
}

// ---------------- K2: Z = E * V / gsum (in place on d_out) ----------------
__global__ __launch_bounds__(256) void finalize_kernel(float* __restrict__ out,
                                                       const float* __restrict__ V,
                                                       const float* __restrict__ gsum) {
  const int total4 = (BATCH*LH) >> 2;
  const int stride = gridDim.x * blockDim.x;
  for (int f = blockIdx.x*blockDim.x + threadIdx.x; f < total4; f += stride) {
    const float4 e = ((const float4*)out)[f];
    const float4 v = ((const float4*)V)[f];
    const int e0 = f << 2;
    const float* gs = gsum + ((e0 >> 21) << 7) + (e0 & 127);   // b*128 + h0
    float4 z;
    z.x = e.x * v.x / gs[0];
    z.y = e.y * v.y / gs[1];
    z.z = e.z * v.z / gs[2];
    z.w = e.w * v.w / gs[3];
    ((float4*)out)[f] = z;
  }
}

extern "C" void kernel_launch(void* const* d_in, const int* in_sizes, int n_in,
                              void* d_out, int out_size, void* d_ws, size_t ws_size,
                              hipStream_t stream) {
  (void)in_sizes; (void)n_in; (void)out_size; (void)ws_size;
  const float* Q = (const float*)d_in[0];
  const float* K = (const float*)d_in[1];
  const float* V = (const float*)d_in[2];
  const float* W = (const float*)d_in[3];
  float* out  = (float*)d_out;
  float* gsum = (float*)d_ws;
  unsigned short* Wbf = (unsigned short*)((char*)d_ws + WS_WBF_OFF);

  hipMemsetAsync(d_ws, 0, BATCH*HDIM*sizeof(float), stream);          // gsum = 0
  wcvt_kernel<<<HDIM, 256, 0, stream>>>(W, Wbf);                      // W -> per-tap frag order
  conv_gate_kernel<<<BATCH*LBLKS, 512, 0, stream>>>(Q, K, Wbf, out, gsum);
  finalize_kernel<<<2048, 256, 0, stream>>>(out, V, gsum);
}